// Round 6
// baseline (152.759 us; speedup 1.0000x reference)
//
#include <hip/hip_runtime.h>

// QuadraticWeightedKappa: N=4194304 rows x 5 classes (f32 logits), int32
// targets. Output: one f32 scalar -kappa.
//
// Correctness model (locked in R5, absmax=0.0): counts = first-max-wins raw
// argmax; finalize = f32 XLA-CPU pipeline with SEQUENTIAL l2r 25-elem sums.
//
// R5 perf: hist 56us, duration identical whether data came from HBM (50MB
// fetch) or LLC (0.5MB fetch) => address-divergence-bound, not BW-bound
// (80B lane stride => 64 lines per load instr). Fix: coalesced float4 loads
// (16B lane stride) staged through LDS (both LDS phases bank-conflict-free:
// byte 80i+16k covers banks {20i+4k..+3} mod 32, each 8-lane group is a
// perfect 32-bank partition). Finalize fused into hist via last-block
// pattern (device-scope atomics + threadfence; atomic read-back).
//
// ws layout: ws[0..24] = confusion counters, ws[25] = done-counter.
// Requires nrows % 1024 == 0 (true: 2^22).

#define KCLS 5

__global__ void kappa_zero_ws(unsigned int* __restrict__ cnt) {
    if (threadIdx.x < 32) cnt[threadIdx.x] = 0u;
}

// XLA CPU full-reduce: init 0.0f, sequential left-to-right adds.
__device__ __forceinline__ float seq25(const float* a) {
    float res = 0.0f;
#pragma unroll
    for (int i = 0; i < 25; ++i) res = __fadd_rn(res, a[i]);
    return res;
}

__device__ void kappa_finalize_device(const unsigned int* cnt, float* out, int n) {
    const float fn = (float)n;  // 2^22, exact
    float conf[25];
#pragma unroll
    for (int k = 0; k < 25; ++k)
        conf[k] = __fdiv_rn((float)cnt[k], fn);  // exact

    float w[25];
#pragma unroll
    for (int i = 0; i < KCLS; ++i)
#pragma unroll
        for (int j = 0; j < KCLS; ++j)
            w[i * KCLS + j] = (float)((i - j) * (i - j)) / 16.0f;  // exact

    // marginals: exact (multiples of 2^-22) -> any order
    float mt[KCLS], mp[KCLS];
#pragma unroll
    for (int i = 0; i < KCLS; ++i) {
        float s = 0.0f;
#pragma unroll
        for (int j = 0; j < KCLS; ++j) s = __fadd_rn(s, conf[i * KCLS + j]);
        mt[i] = s;
    }
#pragma unroll
    for (int j = 0; j < KCLS; ++j) {
        float s = 0.0f;
#pragma unroll
        for (int i = 0; i < KCLS; ++i) s = __fadd_rn(s, conf[i * KCLS + j]);
        mp[j] = s;
    }

    float a[25], b[25];
#pragma unroll
    for (int k = 0; k < 25; ++k) {
        a[k] = __fmul_rn(conf[k], w[k]);                 // RN mul (no FMA)
        float e = __fmul_rn(mt[k / KCLS], mp[k % KCLS]); // outer, RN
        b[k] = __fmul_rn(e, w[k]);                       // RN mul
    }

    float num = seq25(a);
    float den = seq25(b);
    float den2 = __fadd_rn(den, 1e-7f);   // weak scalar -> f32
    float q = __fdiv_rn(num, den2);
    float kappa = __fsub_rn(1.0f, q);
    out[0] = -kappa;
}

__global__ __launch_bounds__(256) void kappa_hist(const float* __restrict__ x,
                                                  const int* __restrict__ tgt,
                                                  unsigned int* __restrict__ ws,
                                                  float* __restrict__ out,
                                                  int nrows, int nblocks) {
    __shared__ float lds[5120];       // 1024 rows x 5 floats = 20 KB staging
    __shared__ unsigned int h[128];   // 4 waves x 32-slot histograms
    const int tid = threadIdx.x;
    if (tid < 128) h[tid] = 0u;

    // coalesced loads: 5x float4, lane-stride 16B
    const float4* xv = (const float4*)x;
    const int bv4 = blockIdx.x * 1280;
    float4 v0 = xv[bv4 + 0 * 256 + tid];
    float4 v1 = xv[bv4 + 1 * 256 + tid];
    float4 v2 = xv[bv4 + 2 * 256 + tid];
    float4 v3 = xv[bv4 + 3 * 256 + tid];
    float4 v4 = xv[bv4 + 4 * 256 + tid];
    const int4 tg = ((const int4*)tgt)[blockIdx.x * 256 + tid];

    float4* lf = (float4*)lds;        // linear b128 writes: conflict-free
    lf[0 * 256 + tid] = v0;
    lf[1 * 256 + tid] = v1;
    lf[2 * 256 + tid] = v2;
    lf[3 * 256 + tid] = v3;
    lf[4 * 256 + tid] = v4;
    __syncthreads();

    unsigned int* hw = h + ((tid >> 6) << 5);
    const float* fr0 = lds + tid * 20;   // 80B/lane: banks partition cleanly
    const int tgv[4] = {tg.x, tg.y, tg.z, tg.w};
#pragma unroll
    for (int r = 0; r < 4; ++r) {
        const float* fr = fr0 + 5 * r;
        // first-occurrence argmax (strict >) == argmax(softmax32(x))
        float m = fr[0];
        int k = 0;
#pragma unroll
        for (int j = 1; j < KCLS; ++j)
            if (fr[j] > m) { m = fr[j]; k = j; }
        atomicAdd(&hw[tgv[r] * KCLS + k], 1u);
    }
    __syncthreads();

    if (tid < KCLS * KCLS) {
        unsigned int s = h[tid] + h[32 + tid] + h[64 + tid] + h[96 + tid];
        if (s) atomicAdd(&ws[tid], s);
    }
    // drain this block's global atomics (compiler emits waitcnt before barrier)
    __syncthreads();

    if (tid == 0) {
        __threadfence();
        unsigned int old = atomicAdd(&ws[25], 1u);
        if (old == (unsigned)(nblocks - 1)) {
            // last block: all 25 counters globally visible; atomic read-back
            unsigned int cnt[25];
#pragma unroll
            for (int k = 0; k < 25; ++k) cnt[k] = atomicAdd(&ws[k], 0u);
            kappa_finalize_device(cnt, out, nrows);
        }
    }
}

extern "C" void kernel_launch(void* const* d_in, const int* in_sizes, int n_in,
                              void* d_out, int out_size, void* d_ws, size_t ws_size,
                              hipStream_t stream) {
    const float* x = (const float*)d_in[0];
    const int* tgt = (const int*)d_in[1];
    float* out = (float*)d_out;
    unsigned int* ws = (unsigned int*)d_ws;

    const int n = in_sizes[1];          // rows (4194304 = 2^22)
    const int nblocks = n / 1024;       // 1024 rows per block (exact)

    kappa_zero_ws<<<1, 32, 0, stream>>>(ws);
    kappa_hist<<<nblocks, 256, 0, stream>>>(x, tgt, ws, out, n, nblocks);
}

// Round 7
// 36.294 us; speedup vs baseline: 4.2089x; 4.2089x over previous
//
#include <hip/hip_runtime.h>

// QuadraticWeightedKappa: N=4194304 rows x 5 classes (f32 logits), int32
// targets. Output: one f32 scalar -kappa.
//
// Correctness model (locked in R5, absmax=0.0): counts = first-max-wins raw
// argmax; finalize = f32 XLA-CPU pipeline with SEQUENTIAL l2r 25-elem sums.
//
// Perf history: R5 = 56us hist, address-divergent loads (80B lane stride,
// 64 reqs/instr). R6 = 210us REGRESSION: per-block __threadfence (device
// fence => cross-XCD L2 invalidate, replays refetch 49MB from HBM) + 8-way
// LDS read conflicts (20-dword lane stride). R7 fixes: 3-dispatch structure
// restored (no fence); LDS staging with CONFLICT-FREE read mapping: thread
// tid reads staged rows {tid, tid+256, ...} => lane stride 5 dwords,
// gcd(5,32)=1 => 2-way bank aliasing (free). Writes = linear ds_write_b128.
// 1024 blocks x 4 stages of 1024 rows.

#define KCLS 5

__global__ __launch_bounds__(256) void kappa_hist(const float* __restrict__ x,
                                                  const int* __restrict__ tgt,
                                                  unsigned int* __restrict__ gcnt) {
    __shared__ float lds[5120];       // 1024 rows x 5 floats = 20 KB
    __shared__ unsigned int h[128];   // 4 waves x 32-slot histograms
    const int tid = threadIdx.x;
    if (tid < 128) h[tid] = 0u;       // barrier before first use is in loop

    const float4* xv = (const float4*)x;
    unsigned int* hw = h + ((tid >> 6) << 5);
    float4* lf = (float4*)lds;

    const int rowbase = blockIdx.x * 4096;   // 4096 rows per block
#pragma unroll 1
    for (int s = 0; s < 4; ++s) {
        const int r0 = rowbase + s * 1024;
        const int bv4 = (r0 / 4) * 5;        // float4 index of stage start
        // coalesced: lane-stride 16B
        float4 v0 = xv[bv4 + 0 * 256 + tid];
        float4 v1 = xv[bv4 + 1 * 256 + tid];
        float4 v2 = xv[bv4 + 2 * 256 + tid];
        float4 v3 = xv[bv4 + 3 * 256 + tid];
        float4 v4 = xv[bv4 + 4 * 256 + tid];
        // targets for the rows this thread will score (coalesced, 4B/lane)
        int tg0 = tgt[r0 + 0 * 256 + tid];
        int tg1 = tgt[r0 + 1 * 256 + tid];
        int tg2 = tgt[r0 + 2 * 256 + tid];
        int tg3 = tgt[r0 + 3 * 256 + tid];

        __syncthreads();   // prev stage's LDS reads done; h init visible (s=0)
        lf[0 * 256 + tid] = v0;
        lf[1 * 256 + tid] = v1;
        lf[2 * 256 + tid] = v2;
        lf[3 * 256 + tid] = v3;
        lf[4 * 256 + tid] = v4;
        __syncthreads();

        const int tgv[4] = {tg0, tg1, tg2, tg3};
#pragma unroll
        for (int r = 0; r < 4; ++r) {
            // row (r*256 + tid): dword addr stride 5 per lane -> 2-way banks
            const float* fr = lds + (r * 256 + tid) * 5;
            float m = fr[0];
            int k = 0;
#pragma unroll
            for (int j = 1; j < KCLS; ++j)
                if (fr[j] > m) { m = fr[j]; k = j; }
            atomicAdd(&hw[tgv[r] * KCLS + k], 1u);
        }
    }
    __syncthreads();

    if (tid < KCLS * KCLS) {
        unsigned int s = h[tid] + h[32 + tid] + h[64 + tid] + h[96 + tid];
        if (s) atomicAdd(&gcnt[tid], s);
    }
}

// XLA CPU full-reduce: init 0.0f, sequential left-to-right adds.
__device__ __forceinline__ float seq25(const float* a) {
    float res = 0.0f;
#pragma unroll
    for (int i = 0; i < 25; ++i) res = __fadd_rn(res, a[i]);
    return res;
}

__global__ void kappa_finalize(const unsigned int* __restrict__ cnt,
                               float* __restrict__ out, int n) {
    if (threadIdx.x != 0 || blockIdx.x != 0) return;

    const float fn = (float)n;  // 2^22, exact
    float conf[25];
#pragma unroll
    for (int k = 0; k < 25; ++k)
        conf[k] = __fdiv_rn((float)cnt[k], fn);  // exact

    float w[25];
#pragma unroll
    for (int i = 0; i < KCLS; ++i)
#pragma unroll
        for (int j = 0; j < KCLS; ++j)
            w[i * KCLS + j] = (float)((i - j) * (i - j)) / 16.0f;  // exact

    float mt[KCLS], mp[KCLS];
#pragma unroll
    for (int i = 0; i < KCLS; ++i) {
        float s = 0.0f;
#pragma unroll
        for (int j = 0; j < KCLS; ++j) s = __fadd_rn(s, conf[i * KCLS + j]);
        mt[i] = s;  // exact: multiples of 2^-22
    }
#pragma unroll
    for (int j = 0; j < KCLS; ++j) {
        float s = 0.0f;
#pragma unroll
        for (int i = 0; i < KCLS; ++i) s = __fadd_rn(s, conf[i * KCLS + j]);
        mp[j] = s;
    }

    float a[25], b[25];
#pragma unroll
    for (int k = 0; k < 25; ++k) {
        a[k] = __fmul_rn(conf[k], w[k]);                 // RN mul (no FMA)
        float e = __fmul_rn(mt[k / KCLS], mp[k % KCLS]); // outer, RN
        b[k] = __fmul_rn(e, w[k]);                       // RN mul
    }

    float num = seq25(a);
    float den = seq25(b);
    float den2 = __fadd_rn(den, 1e-7f);   // weak scalar -> f32
    float q = __fdiv_rn(num, den2);
    float kappa = __fsub_rn(1.0f, q);
    out[0] = -kappa;
}

extern "C" void kernel_launch(void* const* d_in, const int* in_sizes, int n_in,
                              void* d_out, int out_size, void* d_ws, size_t ws_size,
                              hipStream_t stream) {
    const float* x = (const float*)d_in[0];
    const int* tgt = (const int*)d_in[1];
    float* out = (float*)d_out;
    unsigned int* cnt = (unsigned int*)d_ws;

    const int n = in_sizes[1];          // rows (4194304 = 2^22)
    const int nblocks = n / 4096;       // 1024 blocks, 4096 rows each (exact)

    hipMemsetAsync(cnt, 0, 32 * sizeof(unsigned int), stream);
    kappa_hist<<<nblocks, 256, 0, stream>>>(x, tgt, cnt);
    kappa_finalize<<<1, 64, 0, stream>>>(cnt, out, n);
}